// Round 7
// baseline (610.849 us; speedup 1.0000x reference)
//
#include <hip/hip_runtime.h>

typedef __attribute__((ext_vector_type(8))) short short8v;
typedef __attribute__((ext_vector_type(4))) short short4v;
typedef __attribute__((ext_vector_type(4))) float float4v;

#define MFMA16(a,b,c) __builtin_amdgcn_mfma_f32_16x16x32_bf16(a,b,c,0,0,0)

__device__ __forceinline__ unsigned short f2b(float f) {
    union { float f; unsigned u; } v; v.f = f;
    unsigned r = v.u + 0x7FFFu + ((v.u >> 16) & 1u);
    return (unsigned short)(r >> 16);
}
__device__ __forceinline__ float b2f(unsigned short s) {
    union { unsigned u; float f; } v; v.u = ((unsigned)s) << 16;
    return v.f;
}
__device__ __forceinline__ short8v pack8(float4v a, float4v b) {
    short8v o;
    o[0]=(short)f2b(a[0]); o[1]=(short)f2b(a[1]); o[2]=(short)f2b(a[2]); o[3]=(short)f2b(a[3]);
    o[4]=(short)f2b(b[0]); o[5]=(short)f2b(b[1]); o[6]=(short)f2b(b[2]); o[7]=(short)f2b(b[3]);
    return o;
}

// ---------------------------------------------------------------------------
// P1: f32 -> bf16 pack (8 elems/thread). Also used to pack S (n8 = 8M).
// ---------------------------------------------------------------------------
__global__ __launch_bounds__(256) void pack_bf16(
    const float* __restrict__ in, unsigned short* __restrict__ out, int n8) {
    int i = blockIdx.x * 256 + threadIdx.x;
    if (i < n8) {
        float4v a = *(const float4v*)&in[(size_t)i * 8];
        float4v b = *(const float4v*)&in[(size_t)i * 8 + 4];
        *(short8v*)&out[(size_t)i * 8] = pack8(a, b);
    }
}

// ---------------------------------------------------------------------------
// P2: C = hb @ W^T + bias  (MFMA bf16, operands direct from global)
//     vmode 0: out[bh][l][d] bf16      (qh / kh)
//     vmode 1: out[bh][d][r] bf16      (vT)
// ---------------------------------------------------------------------------
__global__ __launch_bounds__(256) void qkv_gemm(
    const unsigned short* __restrict__ A,   // [4096][1024] bf16
    const unsigned short* __restrict__ W,   // [1024][1024] bf16 [n][k]
    const float* __restrict__ bias,         // [1024]
    unsigned short* __restrict__ out, int vmode) {
    const int wave = threadIdx.x >> 6, lane = threadIdx.x & 63;
    const int m0 = blockIdx.y * 128 + wave * 32;
    const int n0 = blockIdx.x * 64;
    const int lrow = lane & 15, g8 = (lane >> 4) << 3, row4 = (lane >> 4) << 2;
    float4v acc[2][4] = {};
    const unsigned short* Ap = A + (size_t)(m0 + lrow) * 1024 + g8;
    const unsigned short* Wp = W + (size_t)(n0 + lrow) * 1024 + g8;
#pragma unroll 2
    for (int k0 = 0; k0 < 1024; k0 += 32) {
        short8v a0 = *(const short8v*)(Ap + k0);
        short8v a1 = *(const short8v*)(Ap + 16 * 1024 + k0);
        short8v b0 = *(const short8v*)(Wp + k0);
        short8v b1 = *(const short8v*)(Wp + 16 * 1024 + k0);
        short8v b2 = *(const short8v*)(Wp + 32 * 1024 + k0);
        short8v b3 = *(const short8v*)(Wp + 48 * 1024 + k0);
        acc[0][0] = MFMA16(a0, b0, acc[0][0]); acc[0][1] = MFMA16(a0, b1, acc[0][1]);
        acc[0][2] = MFMA16(a0, b2, acc[0][2]); acc[0][3] = MFMA16(a0, b3, acc[0][3]);
        acc[1][0] = MFMA16(a1, b0, acc[1][0]); acc[1][1] = MFMA16(a1, b1, acc[1][1]);
        acc[1][2] = MFMA16(a1, b2, acc[1][2]); acc[1][3] = MFMA16(a1, b3, acc[1][3]);
    }
#pragma unroll
    for (int nt = 0; nt < 4; ++nt) {
        const int n = n0 + nt * 16 + lrow;           // C col = lane&15
        const float bz = bias[n];
        const int h = n >> 6, d = n & 63;
#pragma unroll
        for (int mt = 0; mt < 2; ++mt) {
            const int mb = m0 + mt * 16 + row4;      // C row = (lane>>4)*4 + j
            if (vmode == 0) {
#pragma unroll
                for (int j = 0; j < 4; ++j) {
                    const int m = mb + j;
                    const int b = m >> 10, l = m & 1023;
                    out[(((size_t)(b * 16 + h) << 10) + l) * 64 + d] = f2b(acc[mt][nt][j] + bz);
                }
            } else {
                const int b = mb >> 10, r = mb & 1023;
                short4v pk;
#pragma unroll
                for (int j = 0; j < 4; ++j) pk[j] = (short)f2b(acc[mt][nt][j] + bz);
                *(short4v*)&out[((((size_t)(b * 16 + h)) << 6) + d) * 1024 + r] = pk;
            }
        }
    }
}

// ---------------------------------------------------------------------------
// P3: headproj: x2[l][bh][e] = sum_d x[bh][l][d] * Wsx[d][e]   (bf16 out)
//               xbv[l][bh]   = sum_d x[bh][l][d] * bsx[d]
// ---------------------------------------------------------------------------
__global__ __launch_bounds__(256) void headproj(
    const unsigned short* __restrict__ xh,  // [64][1024][64] bf16
    const float* __restrict__ Wsx,          // [64][64] f32
    const float* __restrict__ bsx,          // [64]
    unsigned short* __restrict__ x2b,       // [1024][64][64] bf16
    float* __restrict__ xbv) {              // [1024][64]
    __shared__ __align__(16) float Ws[64 * 64];
    __shared__ float bs[64];
    __shared__ __align__(16) unsigned short Xl[64 * 64];
    const int tid = threadIdx.x;
    const int l = blockIdx.x;
#pragma unroll
    for (int i = 0; i < 4; ++i)
        *(float4v*)&Ws[tid * 4 + i * 1024] = *(const float4v*)&Wsx[tid * 4 + i * 1024];
    if (tid < 64) bs[tid] = bsx[tid];
    {
        const int bhh = tid >> 2, dq = (tid & 3) * 16;
        const unsigned short* src = &xh[((size_t)bhh * 1024 + l) * 64 + dq];
        *(short8v*)&Xl[bhh * 64 + dq] = *(const short8v*)src;
        *(short8v*)&Xl[bhh * 64 + dq + 8] = *(const short8v*)(src + 8);
    }
    __syncthreads();
    const int bh = tid >> 2, e0 = (tid & 3) * 16;
    float acc[16] = {};
    float bacc = 0.f;
    for (int d = 0; d < 64; ++d) {
        const float xd = b2f(Xl[bh * 64 + d]);
        bacc += xd * bs[d];
        const float* wr = &Ws[d * 64 + e0];
#pragma unroll
        for (int e = 0; e < 16; e += 4) {
            float4v w = *(const float4v*)&wr[e];
            acc[e] += xd * w[0]; acc[e + 1] += xd * w[1];
            acc[e + 2] += xd * w[2]; acc[e + 3] += xd * w[3];
        }
    }
    short8v p0, p1;
#pragma unroll
    for (int e = 0; e < 8; ++e) { p0[e] = (short)f2b(acc[e]); p1[e] = (short)f2b(acc[e + 8]); }
    unsigned short* dst = &x2b[((size_t)l * 64 + bh) * 64 + e0];
    *(short8v*)dst = p0; *(short8v*)(dst + 8) = p1;
    if ((tid & 3) == 0) xbv[l * 64 + bh] = bacc;
}

// ---------------------------------------------------------------------------
// P4 v7: fused structure-bias kernel with BATCHED register prefetch.
//   sb[l][bh][r] = sum_d S[l][r][d]*(q2[l][bh][d] + k2[r][bh][d]) + qb + kb
// Block = 16l x 16r tile, 4 waves; wave w owns bh in [16w,16w+16).
// The R5/R6 kernels were serial-latency-bound (VGPR=84 left no room to
// pipeline the per-iteration k2b/q2b loads: ~48 dependent ~600cy loads per
// block). v7 issues the B-operands in 8-iteration register batches (16
// back-to-back loads -> one latency payment), launch_bounds(256,2).
// ---------------------------------------------------------------------------
__global__ __launch_bounds__(256, 2) void struct_fused(
    const unsigned short* __restrict__ Sb,    // [1024][1024][64] bf16
    const unsigned short* __restrict__ q2b,   // [1024][64][64] bf16
    const unsigned short* __restrict__ k2b,   // [1024][64][64] bf16
    const float* __restrict__ qbv,            // [1024][64]
    const float* __restrict__ kbv,            // [1024][64]
    unsigned short* __restrict__ sb) {        // [1024][64][1024] bf16
    __shared__ __align__(16) unsigned short Ssh[256 * 64];       // 32 KB
    __shared__ __align__(16) unsigned short t3g[4][4][16][16];   // 8 KB
    const int tid = threadIdx.x;
    const int w = tid >> 6, lane = tid & 63;
    const int lrow = lane & 15, g = lane >> 4;
    const int g8 = g << 3, row4 = g << 2;
    const int w16 = w << 4;
    const int r0 = blockIdx.x << 4, l0 = blockIdx.y << 4;

    // ---- stage Sb tile via async DMA; swizzle on the global source ----
    {
        const int lrow8 = lane >> 3, lslot = lane & 7;
#pragma unroll
        for (int i = 0; i < 8; ++i) {
            const int row = (w << 6) + (i << 3) + lrow8;
            const int cg = lslot ^ ((row ^ (row >> 4)) & 7);
            const unsigned short* src =
                Sb + ((size_t)(l0 + (row >> 4)) * 1024 + r0 + (row & 15)) * 64 + (cg << 3);
            unsigned short* dst = (unsigned short*)Ssh + (size_t)((w << 6) + (i << 3)) * 64;
            __builtin_amdgcn_global_load_lds(
                (const __attribute__((address_space(1))) void*)src,
                (__attribute__((address_space(3))) void*)dst, 16, 0, 0);
        }
    }
    // ---- batch-issue T3 half-0 B operands + kb biases (fly with the DMA) --
    short8v ka0[8], ka1[8];
#pragma unroll
    for (int i = 0; i < 8; ++i) {
        const unsigned short* Bp = k2b + ((size_t)(r0 + i) * 64 + w16 + lrow) * 64 + g8;
        ka0[i] = *(const short8v*)Bp;
        ka1[i] = *(const short8v*)(Bp + 32);
    }
    float kbreg[4];
#pragma unroll
    for (int j = 0; j < 4; ++j)
        kbreg[j] = kbv[(size_t)(r0 + row4 + j) * 64 + w16 + lrow];
    asm volatile("s_waitcnt vmcnt(0)" ::: "memory");
    __syncthreads();

    // ---- batch-issue T3 half-1 B operands (in flight during half-0) ----
    short8v kc0[8], kc1[8];
#pragma unroll
    for (int i = 0; i < 8; ++i) {
        const unsigned short* Bp = k2b + ((size_t)(r0 + 8 + i) * 64 + w16 + lrow) * 64 + g8;
        kc0[i] = *(const short8v*)Bp;
        kc1[i] = *(const short8v*)(Bp + 32);
    }

    // ---- T3 compute: c3[ri][j] = t3(l=4g+j, bh=w16+lrow, r=r0+ri) ----
    float4v c3[16];
#pragma unroll
    for (int ri = 0; ri < 8; ++ri) {
        const int row = lrow * 16 + ri;
        const int key = (lrow ^ ri) & 7;
        short8v a0 = *(const short8v*)&Ssh[row * 64 + ((g ^ key) << 3)];
        short8v a1 = *(const short8v*)&Ssh[row * 64 + (((4 + g) ^ key) << 3)];
        c3[ri] = MFMA16(a1, ka1[ri], MFMA16(a0, ka0[ri], float4v{}));
    }
    // ---- batch-issue T2 half-0 (li 0..7) q2b operands + qb biases ----
    short8v qa0[8], qa1[8];
#pragma unroll
    for (int i = 0; i < 8; ++i) {
        const unsigned short* Bp = q2b + ((size_t)(l0 + i) * 64 + w16 + lrow) * 64 + g8;
        qa0[i] = *(const short8v*)Bp;
        qa1[i] = *(const short8v*)(Bp + 32);
    }
    float qbreg[16];
#pragma unroll
    for (int li = 0; li < 16; ++li)
        qbreg[li] = qbv[(size_t)(l0 + li) * 64 + w16 + lrow];
#pragma unroll
    for (int ri = 8; ri < 16; ++ri) {
        const int row = lrow * 16 + ri;
        const int key = (lrow ^ ri) & 7;
        short8v a0 = *(const short8v*)&Ssh[row * 64 + ((g ^ key) << 3)];
        short8v a1 = *(const short8v*)&Ssh[row * 64 + (((4 + g) ^ key) << 3)];
        c3[ri] = MFMA16(a1, kc1[ri - 8], MFMA16(a0, kc0[ri - 8], float4v{}));
    }

    // ---- T2 in 4 li-groups; JIT dump of the matching T3 slice ----
#pragma unroll
    for (int G = 0; G < 4; ++G) {
        if (G == 2) {
            // batch-issue T2 half-1 (li 8..15) — hidden under groups 2-3
        }
        if (g == G) {
            // thread (lrow, G) holds t3(l=4G+j, bh=w16+lrow, r=r0+ri) in c3[ri][j]
#pragma unroll
            for (int j = 0; j < 4; ++j) {
                short8v lo, hi;
#pragma unroll
                for (int i = 0; i < 8; ++i) {
                    lo[i] = (short)f2b(c3[i][j]);
                    hi[i] = (short)f2b(c3[8 + i][j]);
                }
                *(short8v*)&t3g[w][j][lrow][0] = lo;
                *(short8v*)&t3g[w][j][lrow][8] = hi;
            }
        }
        // wave-local: ensure dump landed before this group's t3 reads.
        asm volatile("s_waitcnt lgkmcnt(0)" ::: "memory");
#pragma unroll
        for (int lj = 0; lj < 4; ++lj) {
            const int li = (G << 2) + lj;
            const int row = li * 16 + lrow;
            const int key = (li ^ lrow) & 7;
            short8v a0 = *(const short8v*)&Ssh[row * 64 + ((g ^ key) << 3)];
            short8v a1 = *(const short8v*)&Ssh[row * 64 + (((4 + g) ^ key) << 3)];
            short8v b0, b1;
            if (li < 8) { b0 = qa0[li & 7]; b1 = qa1[li & 7]; }
            else {
                const unsigned short* Bp = q2b + ((size_t)(l0 + li) * 64 + w16 + lrow) * 64 + g8;
                b0 = *(const short8v*)Bp;
                b1 = *(const short8v*)(Bp + 32);
            }
            float4v c2 = MFMA16(a1, b1, MFMA16(a0, b0, float4v{}));
            // t3(l=li, bh=w16+lrow, r=r0+4g+j)
            short4v t3v = *(const short4v*)&t3g[w][lj][lrow][row4];
            const float qb = qbreg[li];
            short4v outv;
#pragma unroll
            for (int j = 0; j < 4; ++j)
                outv[j] = (short)f2b(c2[j] + b2f((unsigned short)t3v[j]) + qb + kbreg[j]);
            // direct store: lane (lrow,g) covers r = r0+4g..4g+3 for bh=w16+lrow
            *(short4v*)&sb[((size_t)(l0 + li) * 64 + w16 + lrow) * 1024 + r0 + row4] = outv;
        }
    }
}

// ---------------------------------------------------------------------------
// P6: flash: scores[bh][l][r] = (QK + sb)*0.125 + mask; online softmax; PV.
// ---------------------------------------------------------------------------
__global__ __launch_bounds__(256) void flash_kernel(
    const unsigned short* __restrict__ qh,  // [64][1024][64] bf16
    const unsigned short* __restrict__ kh,
    const unsigned short* __restrict__ vT,  // [64][64][1024] bf16
    const unsigned short* __restrict__ sb,  // [1024][64][1024] bf16
    const float* __restrict__ mask,         // [4][1024]
    float* __restrict__ scores,             // [64][1024][1024]
    float* __restrict__ ctx) {              // [4][1024][1024]
    __shared__ __align__(16) float scL[32 * 64];
    __shared__ __align__(16) unsigned short pL[32 * 64];
    __shared__ float mL[32], sL[32], fL[32];
    const int bid = blockIdx.x;
    const int virt = (bid & 7) * 256 + (bid >> 3);
    const int bh = virt >> 5, lt = virt & 31;
    const int b = bh >> 4, h = bh & 15, l0 = lt * 32;
    const int tid = threadIdx.x, wave = tid >> 6, lane = tid & 63;
    const int lrow = lane & 15, g8 = (lane >> 4) << 3, row4 = (lane >> 4) << 2;
    short8v qf[2][2];
#pragma unroll
    for (int mt = 0; mt < 2; ++mt)
#pragma unroll
        for (int ks = 0; ks < 2; ++ks)
            qf[mt][ks] = *(const short8v*)&qh[((size_t)bh * 1024 + l0 + mt * 16 + lrow) * 64 + ks * 32 + g8];
    float4v opv[2] = {};
    if (tid < 32) { mL[tid] = -3e38f; sL[tid] = 0.f; }
    __syncthreads();
    const int tl = tid >> 3, tr8 = tid & 7;
    const int keyS = ((tl >> 2) & 3) << 4;
    const int keyP = (tl & 7) << 3;
    for (int rt = 0; rt < 16; ++rt) {
        const int r0 = rt * 64;
        float4v sacc[2] = {};
#pragma unroll
        for (int ks = 0; ks < 2; ++ks) {
            short8v kf = *(const short8v*)&kh[((size_t)bh * 1024 + r0 + wave * 16 + lrow) * 64 + ks * 32 + g8];
            sacc[0] = MFMA16(qf[0][ks], kf, sacc[0]);
            sacc[1] = MFMA16(qf[1][ks], kf, sacc[1]);
        }
#pragma unroll
        for (int mt = 0; mt < 2; ++mt)
#pragma unroll
            for (int j = 0; j < 4; ++j) {
                const int ll = mt * 16 + row4 + j;
                const int cc = wave * 16 + lrow;
                scL[ll * 64 + (cc ^ (((ll >> 2) & 3) << 4))] = sacc[mt][j];
            }
        __syncthreads();
        float4v x0 = *(const float4v*)&scL[tl * 64 + ((tr8 * 8) ^ keyS)];
        float4v x1 = *(const float4v*)&scL[tl * 64 + ((tr8 * 8 + 4) ^ keyS)];
        short8v sbv = *(const short8v*)&sb[((size_t)(l0 + tl) * 64 + bh) * 1024 + r0 + tr8 * 8];
        float4v mk0 = *(const float4v*)&mask[(size_t)b * 1024 + r0 + tr8 * 8];
        float4v mk1 = *(const float4v*)&mask[(size_t)b * 1024 + r0 + tr8 * 8 + 4];
        float s8[8];
#pragma unroll
        for (int i = 0; i < 4; ++i) {
            s8[i]     = (x0[i] + b2f((unsigned short)sbv[i])) * 0.125f + mk0[i];
            s8[i + 4] = (x1[i] + b2f((unsigned short)sbv[i + 4])) * 0.125f + mk1[i];
        }
        {
            float4v o0, o1;
#pragma unroll
            for (int i = 0; i < 4; ++i) { o0[i] = s8[i]; o1[i] = s8[i + 4]; }
            float* sgp = &scores[((size_t)bh * 1024 + l0 + tl) * 1024 + r0 + tr8 * 8];
            *(float4v*)sgp = o0; *(float4v*)(sgp + 4) = o1;
        }
        float tm = s8[0];
#pragma unroll
        for (int i = 1; i < 8; ++i) tm = fmaxf(tm, s8[i]);
        tm = fmaxf(tm, __shfl_xor(tm, 1));
        tm = fmaxf(tm, __shfl_xor(tm, 2));
        tm = fmaxf(tm, __shfl_xor(tm, 4));
        const float mold = mL[tl];
        const float mnew = fmaxf(mold, tm);
        const float f = __expf(mold - mnew);
        float psum = 0.f;
        float p8[8];
#pragma unroll
        for (int i = 0; i < 8; ++i) { p8[i] = __expf(s8[i] - mnew); psum += p8[i]; }
        psum += __shfl_xor(psum, 1);
        psum += __shfl_xor(psum, 2);
        psum += __shfl_xor(psum, 4);
        if (tr8 == 0) { sL[tl] = sL[tl] * f + psum; mL[tl] = mnew; fL[tl] = f; }
        short8v pk;
#pragma unroll
        for (int i = 0; i < 8; ++i) pk[i] = (short)f2b(p8[i]);
        *(short8v*)&pL[tl * 64 + ((tr8 * 8) ^ keyP)] = pk;
        __syncthreads();
#pragma unroll
        for (int mt = 0; mt < 2; ++mt)
#pragma unroll
            for (int j = 0; j < 4; ++j) opv[mt][j] *= fL[mt * 16 + row4 + j];
#pragma unroll
        for (int ks = 0; ks < 2; ++ks) {
            short8v pf0 = *(const short8v*)&pL[(lrow) * 64 + ((ks * 32 + g8) ^ ((lrow & 7) << 3))];
            short8v pf1 = *(const short8v*)&pL[(16 + lrow) * 64 + ((ks * 32 + g8) ^ ((lrow & 7) << 3))];
            short8v vf = *(const short8v*)&vT[((size_t)bh * 64 + wave * 16 + lrow) * 1024 + r0 + ks * 32 + g8];
            opv[0] = MFMA16(pf0, vf, opv[0]);
            opv[1] = MFMA16(pf1, vf, opv[1]);
        }
    }
#pragma unroll
    for (int mt = 0; mt < 2; ++mt)
#pragma unroll
        for (int j = 0; j < 4; ++j) {
            const int l = mt * 16 + row4 + j;
            const float inv = 1.f / sL[l];
            const int d = wave * 16 + lrow;
            ctx[((size_t)b * 1024 + l0 + l) * 1024 + h * 64 + d] = opv[mt][j] * inv;
        }
}

// ---------------------------------------------------------------------------
extern "C" void kernel_launch(void* const* d_in, const int* in_sizes, int n_in,
                              void* d_out, int out_size, void* d_ws, size_t ws_size,
                              hipStream_t stream) {
    (void)in_sizes; (void)n_in; (void)out_size; (void)ws_size;
    const float* hidden = (const float*)d_in[0];
    const float* mask   = (const float*)d_in[1];
    const float* S      = (const float*)d_in[2];
    const float* Wq  = (const float*)d_in[3];  const float* bq  = (const float*)d_in[4];
    const float* Wk  = (const float*)d_in[5];  const float* bk  = (const float*)d_in[6];
    const float* Wv  = (const float*)d_in[7];  const float* bv  = (const float*)d_in[8];
    const float* Wsq = (const float*)d_in[9];  const float* bsq = (const float*)d_in[10];
    const float* Wsk = (const float*)d_in[11]; const float* bsk = (const float*)d_in[12];

    float* ctx    = (float*)d_out;
    float* scores = ctx + (size_t)4 * 1024 * 1024;

    char* ws = (char*)d_ws;
    unsigned short* sbuf = (unsigned short*)ws;                 // [1024][64][1024] bf16, 128 MB
    unsigned short* hb  = (unsigned short*)ws;                  // stage-1 temps alias sbuf
    unsigned short* Wqb = (unsigned short*)(ws + (8u << 20));
    unsigned short* Wkb = (unsigned short*)(ws + (10u << 20));
    unsigned short* Wvb = (unsigned short*)(ws + (12u << 20));
    unsigned short* qh  = (unsigned short*)(ws + (size_t)(128u) * 1024 * 1024);
    unsigned short* kh  = qh  + (size_t)4 * 1024 * 1024;
    unsigned short* vT  = kh  + (size_t)4 * 1024 * 1024;
    unsigned short* q2b = vT  + (size_t)4 * 1024 * 1024;
    unsigned short* k2b = q2b + (size_t)4 * 1024 * 1024;
    float* qbv = (float*)(k2b + (size_t)4 * 1024 * 1024);
    float* kbv = qbv + 65536;
    // Sb (bf16 S, 128 MB) lives in the not-yet-written scores region of d_out
    unsigned short* Sbuf = (unsigned short*)scores;

    pack_bf16<<<2048, 256, 0, stream>>>(hidden, hb, 524288);
    pack_bf16<<<512, 256, 0, stream>>>(Wq, Wqb, 131072);
    pack_bf16<<<512, 256, 0, stream>>>(Wk, Wkb, 131072);
    pack_bf16<<<512, 256, 0, stream>>>(Wv, Wvb, 131072);
    pack_bf16<<<32768, 256, 0, stream>>>(S, Sbuf, 8388608);
    qkv_gemm<<<dim3(16, 32), 256, 0, stream>>>(hb, Wqb, bq, qh, 0);
    qkv_gemm<<<dim3(16, 32), 256, 0, stream>>>(hb, Wkb, bk, kh, 0);
    qkv_gemm<<<dim3(16, 32), 256, 0, stream>>>(hb, Wvb, bv, vT, 1);
    headproj<<<1024, 256, 0, stream>>>(qh, Wsq, bsq, q2b, qbv);
    headproj<<<1024, 256, 0, stream>>>(kh, Wsk, bsk, k2b, kbv);
    struct_fused<<<dim3(64, 64), 256, 0, stream>>>(Sbuf, q2b, k2b, qbv, kbv, sbuf);
    flash_kernel<<<2048, 256, 0, stream>>>(qh, kh, vT, sbuf, mask, scores, ctx);
}

// Round 8
// 535.928 us; speedup vs baseline: 1.1398x; 1.1398x over previous
//
#include <hip/hip_runtime.h>

typedef __attribute__((ext_vector_type(8))) short short8v;
typedef __attribute__((ext_vector_type(4))) short short4v;
typedef __attribute__((ext_vector_type(4))) float float4v;

#define MFMA16(a,b,c) __builtin_amdgcn_mfma_f32_16x16x32_bf16(a,b,c,0,0,0)

__device__ __forceinline__ unsigned short f2b(float f) {
    union { float f; unsigned u; } v; v.f = f;
    unsigned r = v.u + 0x7FFFu + ((v.u >> 16) & 1u);
    return (unsigned short)(r >> 16);
}
__device__ __forceinline__ float b2f(unsigned short s) {
    union { unsigned u; float f; } v; v.u = ((unsigned)s) << 16;
    return v.f;
}
// RNE f32x8 -> bf16x8 via v_cvt_pk_bf16_f32 (same rounding as f2b)
__device__ __forceinline__ short8v pack8(float4v a, float4v b) {
    union { unsigned u[4]; short8v s; } o;
    asm("v_cvt_pk_bf16_f32 %0, %1, %2" : "=v"(o.u[0]) : "v"(a[0]), "v"(a[1]));
    asm("v_cvt_pk_bf16_f32 %0, %1, %2" : "=v"(o.u[1]) : "v"(a[2]), "v"(a[3]));
    asm("v_cvt_pk_bf16_f32 %0, %1, %2" : "=v"(o.u[2]) : "v"(b[0]), "v"(b[1]));
    asm("v_cvt_pk_bf16_f32 %0, %1, %2" : "=v"(o.u[3]) : "v"(b[2]), "v"(b[3]));
    return o.s;
}

// ---------------------------------------------------------------------------
// P1: consolidated f32 -> bf16 pack for hidden / Wq / Wk / Wv (one launch).
// blocks 0..2047 hidden (4M elems), then 512 each for Wq/Wk/Wv (1M each).
// ---------------------------------------------------------------------------
__global__ __launch_bounds__(256) void pack_all(
    const float* __restrict__ hidden, const float* __restrict__ Wq,
    const float* __restrict__ Wk, const float* __restrict__ Wv,
    unsigned short* __restrict__ hb, unsigned short* __restrict__ Wqb,
    unsigned short* __restrict__ Wkb, unsigned short* __restrict__ Wvb) {
    const int bid = blockIdx.x;
    const float* in; unsigned short* out; int i;
    if (bid < 2048)      { in = hidden; out = hb;  i = bid * 256 + threadIdx.x; }
    else if (bid < 2560) { in = Wq; out = Wqb; i = (bid - 2048) * 256 + threadIdx.x; }
    else if (bid < 3072) { in = Wk; out = Wkb; i = (bid - 2560) * 256 + threadIdx.x; }
    else                 { in = Wv; out = Wvb; i = (bid - 3072) * 256 + threadIdx.x; }
    float4v a = *(const float4v*)&in[(size_t)i * 8];
    float4v b = *(const float4v*)&in[(size_t)i * 8 + 4];
    *(short8v*)&out[(size_t)i * 8] = pack8(a, b);
}

// ---------------------------------------------------------------------------
// P2: C = hb @ W^T + bias  (MFMA bf16, operands direct from global)
//     vmode 0: out[bh][l][d] bf16      (qh / kh)
//     vmode 1: out[bh][d][r] bf16      (vT)
// ---------------------------------------------------------------------------
__global__ __launch_bounds__(256) void qkv_gemm(
    const unsigned short* __restrict__ A,   // [4096][1024] bf16
    const unsigned short* __restrict__ W,   // [1024][1024] bf16 [n][k]
    const float* __restrict__ bias,         // [1024]
    unsigned short* __restrict__ out, int vmode) {
    const int wave = threadIdx.x >> 6, lane = threadIdx.x & 63;
    const int m0 = blockIdx.y * 128 + wave * 32;
    const int n0 = blockIdx.x * 64;
    const int lrow = lane & 15, g8 = (lane >> 4) << 3, row4 = (lane >> 4) << 2;
    float4v acc[2][4] = {};
    const unsigned short* Ap = A + (size_t)(m0 + lrow) * 1024 + g8;
    const unsigned short* Wp = W + (size_t)(n0 + lrow) * 1024 + g8;
#pragma unroll 2
    for (int k0 = 0; k0 < 1024; k0 += 32) {
        short8v a0 = *(const short8v*)(Ap + k0);
        short8v a1 = *(const short8v*)(Ap + 16 * 1024 + k0);
        short8v b0 = *(const short8v*)(Wp + k0);
        short8v b1 = *(const short8v*)(Wp + 16 * 1024 + k0);
        short8v b2 = *(const short8v*)(Wp + 32 * 1024 + k0);
        short8v b3 = *(const short8v*)(Wp + 48 * 1024 + k0);
        acc[0][0] = MFMA16(a0, b0, acc[0][0]); acc[0][1] = MFMA16(a0, b1, acc[0][1]);
        acc[0][2] = MFMA16(a0, b2, acc[0][2]); acc[0][3] = MFMA16(a0, b3, acc[0][3]);
        acc[1][0] = MFMA16(a1, b0, acc[1][0]); acc[1][1] = MFMA16(a1, b1, acc[1][1]);
        acc[1][2] = MFMA16(a1, b2, acc[1][2]); acc[1][3] = MFMA16(a1, b3, acc[1][3]);
    }
#pragma unroll
    for (int nt = 0; nt < 4; ++nt) {
        const int n = n0 + nt * 16 + lrow;           // C col = lane&15
        const float bz = bias[n];
        const int h = n >> 6, d = n & 63;
#pragma unroll
        for (int mt = 0; mt < 2; ++mt) {
            const int mb = m0 + mt * 16 + row4;      // C row = (lane>>4)*4 + j
            if (vmode == 0) {
#pragma unroll
                for (int j = 0; j < 4; ++j) {
                    const int m = mb + j;
                    const int b = m >> 10, l = m & 1023;
                    out[(((size_t)(b * 16 + h) << 10) + l) * 64 + d] = f2b(acc[mt][nt][j] + bz);
                }
            } else {
                const int b = mb >> 10, r = mb & 1023;
                short4v pk;
#pragma unroll
                for (int j = 0; j < 4; ++j) pk[j] = (short)f2b(acc[mt][nt][j] + bz);
                *(short4v*)&out[((((size_t)(b * 16 + h)) << 6) + d) * 1024 + r] = pk;
            }
        }
    }
}

// ---------------------------------------------------------------------------
// P3: headproj: x2[l][bh][e] = sum_d x[bh][l][d] * Wsx[d][e]   (bf16 out)
//               xbv[l][bh]   = sum_d x[bh][l][d] * bsx[d]
// ---------------------------------------------------------------------------
__global__ __launch_bounds__(256) void headproj(
    const unsigned short* __restrict__ xh,  // [64][1024][64] bf16
    const float* __restrict__ Wsx,          // [64][64] f32
    const float* __restrict__ bsx,          // [64]
    unsigned short* __restrict__ x2b,       // [1024][64][64] bf16
    float* __restrict__ xbv) {              // [1024][64]
    __shared__ __align__(16) float Ws[64 * 64];
    __shared__ float bs[64];
    __shared__ __align__(16) unsigned short Xl[64 * 64];
    const int tid = threadIdx.x;
    const int l = blockIdx.x;
#pragma unroll
    for (int i = 0; i < 4; ++i)
        *(float4v*)&Ws[tid * 4 + i * 1024] = *(const float4v*)&Wsx[tid * 4 + i * 1024];
    if (tid < 64) bs[tid] = bsx[tid];
    {
        const int bhh = tid >> 2, dq = (tid & 3) * 16;
        const unsigned short* src = &xh[((size_t)bhh * 1024 + l) * 64 + dq];
        *(short8v*)&Xl[bhh * 64 + dq] = *(const short8v*)src;
        *(short8v*)&Xl[bhh * 64 + dq + 8] = *(const short8v*)(src + 8);
    }
    __syncthreads();
    const int bh = tid >> 2, e0 = (tid & 3) * 16;
    float acc[16] = {};
    float bacc = 0.f;
    for (int d = 0; d < 64; ++d) {
        const float xd = b2f(Xl[bh * 64 + d]);
        bacc += xd * bs[d];
        const float* wr = &Ws[d * 64 + e0];
#pragma unroll
        for (int e = 0; e < 16; e += 4) {
            float4v w = *(const float4v*)&wr[e];
            acc[e] += xd * w[0]; acc[e + 1] += xd * w[1];
            acc[e + 2] += xd * w[2]; acc[e + 3] += xd * w[3];
        }
    }
    short8v p0, p1;
#pragma unroll
    for (int e = 0; e < 8; ++e) { p0[e] = (short)f2b(acc[e]); p1[e] = (short)f2b(acc[e + 8]); }
    unsigned short* dst = &x2b[((size_t)l * 64 + bh) * 64 + e0];
    *(short8v*)dst = p0; *(short8v*)(dst + 8) = p1;
    if ((tid & 3) == 0) xbv[l * 64 + bh] = bacc;
}

// ---------------------------------------------------------------------------
// P4 v8: fused structure-bias kernel — f32 S staged DIRECTLY via DMA
// (no packS pass, no Sb buffer), fragments converted f32->bf16 in-register.
//   sb[l][bh][r] = sum_d S[l][r][d]*(q2[l][bh][d] + k2[r][bh][d]) + qb + kb
// Block = 16l x 16r tile, 4 waves; wave w owns bh in [16w,16w+16).
// XOR swizzle on 32-B chunk-PAIRS (preserves float4-pair contiguity),
// key(row) = (row ^ row>>4) & 7 — varies with lane for both T3/T2 reads.
// LDS: Ssh 64 KB f32 + t3g 8 KB = 72 KB -> 2 blocks/CU.
// ---------------------------------------------------------------------------
__global__ __launch_bounds__(256, 2) void struct_fused(
    const float* __restrict__ S,              // [1024][1024][64] f32
    const unsigned short* __restrict__ q2b,   // [1024][64][64] bf16
    const unsigned short* __restrict__ k2b,   // [1024][64][64] bf16
    const float* __restrict__ qbv,            // [1024][64]
    const float* __restrict__ kbv,            // [1024][64]
    unsigned short* __restrict__ sb) {        // [1024][64][1024] bf16
    __shared__ __align__(16) float Ssh[256 * 64];                // 64 KB
    __shared__ __align__(16) unsigned short t3g[4][4][16][16];   // 8 KB
    const int tid = threadIdx.x;
    const int w = tid >> 6, lane = tid & 63;
    const int lrow = lane & 15, g = lane >> 4;
    const int g8 = g << 3, row4 = g << 2;
    const int w16 = w << 4;
    const int r0 = blockIdx.x << 4, l0 = blockIdx.y << 4;

    // ---- stage f32 S tile via async DMA; pair-swizzle on global source ----
    // dest linear: instr i covers rows w*64+i*4 .. +3 (256 B each);
    // lane: rowoff = lane>>4, chunk c = lane&15 (16-B units).
    // source fetches chunk ((c>>1 ^ key)<<1 | (c&1)) so a linear LDS read at
    // phys pair p yields logical pair p ^ key(row).
    {
        const int rowoff = lane >> 4, c = lane & 15;
#pragma unroll
        for (int i = 0; i < 16; ++i) {
            const int row = (w << 6) + (i << 2) + rowoff;
            const int key = (row ^ (row >> 4)) & 7;
            const int sc = ((((c >> 1) ^ key) << 1) | (c & 1));
            const float* src =
                S + ((size_t)(l0 + (row >> 4)) * 1024 + r0 + (row & 15)) * 64 + (sc << 2);
            float* dst = Ssh + (size_t)((w << 6) + (i << 2)) * 64;
            __builtin_amdgcn_global_load_lds(
                (const __attribute__((address_space(1))) void*)src,
                (__attribute__((address_space(3))) void*)dst, 16, 0, 0);
        }
    }
    float kbreg[4];
#pragma unroll
    for (int j = 0; j < 4; ++j)
        kbreg[j] = kbv[(size_t)(r0 + row4 + j) * 64 + w16 + lrow];
    asm volatile("s_waitcnt vmcnt(0)" ::: "memory");
    __syncthreads();

    // ---- T3: per ri, A rows = l (lane&15); B = k2[r0+ri][bh-group] ----
    // c3[ri][j] at lane (lrow,g) = t3(l = 4g+j, bh = w16+lrow, r = r0+ri)
    float4v c3[16];
#pragma unroll
    for (int ri = 0; ri < 16; ++ri) {
        const int row = lrow * 16 + ri;
        const int key = (lrow ^ ri) & 7;
        const float* pr = Ssh + row * 64;
        const int p0 = (g ^ key) << 3, p1 = ((4 + g) ^ key) << 3;
        short8v a0 = pack8(*(const float4v*)(pr + p0), *(const float4v*)(pr + p0 + 4));
        short8v a1 = pack8(*(const float4v*)(pr + p1), *(const float4v*)(pr + p1 + 4));
        const unsigned short* Bp = k2b + ((size_t)(r0 + ri) * 64 + w16 + lrow) * 64 + g8;
        short8v b0 = *(const short8v*)Bp;
        short8v b1 = *(const short8v*)(Bp + 32);
        float4v acc = {};
        acc = MFMA16(a0, b0, acc);
        acc = MFMA16(a1, b1, acc);
        c3[ri] = acc;
    }

    // ---- T2 in 4 li-groups; JIT dump of the matching T3 slice ----
#pragma unroll
    for (int G = 0; G < 4; ++G) {
        if (g == G) {
            // thread (lrow, G) holds t3(l=4G+j, bh=w16+lrow, r=r0+ri) in c3[ri][j]
#pragma unroll
            for (int j = 0; j < 4; ++j) {
                short8v lo, hi;
                float4v la{c3[0][j], c3[1][j], c3[2][j], c3[3][j]};
                float4v lb{c3[4][j], c3[5][j], c3[6][j], c3[7][j]};
                float4v ha{c3[8][j], c3[9][j], c3[10][j], c3[11][j]};
                float4v hb{c3[12][j], c3[13][j], c3[14][j], c3[15][j]};
                lo = pack8(la, lb); hi = pack8(ha, hb);
                *(short8v*)&t3g[w][j][lrow][0] = lo;
                *(short8v*)&t3g[w][j][lrow][8] = hi;
            }
        }
        // wave-local: ensure dump landed before this group's t3 reads.
        asm volatile("s_waitcnt lgkmcnt(0)" ::: "memory");
#pragma unroll
        for (int lj = 0; lj < 4; ++lj) {
            const int li = (G << 2) + lj;
            const int row = li * 16 + lrow;
            const int key = (li ^ lrow) & 7;
            const float* pr = Ssh + row * 64;
            const int p0 = (g ^ key) << 3, p1 = ((4 + g) ^ key) << 3;
            short8v a0 = pack8(*(const float4v*)(pr + p0), *(const float4v*)(pr + p0 + 4));
            short8v a1 = pack8(*(const float4v*)(pr + p1), *(const float4v*)(pr + p1 + 4));
            const unsigned short* Bp = q2b + ((size_t)(l0 + li) * 64 + w16 + lrow) * 64 + g8;
            short8v b0 = *(const short8v*)Bp;
            short8v b1 = *(const short8v*)(Bp + 32);
            float4v c2 = {};
            c2 = MFMA16(a0, b0, c2);
            c2 = MFMA16(a1, b1, c2);
            // t3(l=li, bh=w16+lrow, r=r0+4g+j)
            short4v t3v = *(const short4v*)&t3g[w][lj][lrow][row4];
            const float qb = qbv[(size_t)(l0 + li) * 64 + w16 + lrow];
            short4v outv;
#pragma unroll
            for (int j = 0; j < 4; ++j)
                outv[j] = (short)f2b(c2[j] + b2f((unsigned short)t3v[j]) + qb + kbreg[j]);
            // direct store: lane (lrow,g) covers r = r0+4g..4g+3 for bh=w16+lrow
            *(short4v*)&sb[((size_t)(l0 + li) * 64 + w16 + lrow) * 1024 + r0 + row4] = outv;
        }
    }
}

// ---------------------------------------------------------------------------
// P6: flash: scores[bh][l][r] = (QK + sb)*0.125 + mask; online softmax; PV.
// ---------------------------------------------------------------------------
__global__ __launch_bounds__(256) void flash_kernel(
    const unsigned short* __restrict__ qh,  // [64][1024][64] bf16
    const unsigned short* __restrict__ kh,
    const unsigned short* __restrict__ vT,  // [64][64][1024] bf16
    const unsigned short* __restrict__ sb,  // [1024][64][1024] bf16
    const float* __restrict__ mask,         // [4][1024]
    float* __restrict__ scores,             // [64][1024][1024]
    float* __restrict__ ctx) {              // [4][1024][1024]
    __shared__ __align__(16) float scL[32 * 64];
    __shared__ __align__(16) unsigned short pL[32 * 64];
    __shared__ float mL[32], sL[32], fL[32];
    const int bid = blockIdx.x;
    const int virt = (bid & 7) * 256 + (bid >> 3);
    const int bh = virt >> 5, lt = virt & 31;
    const int b = bh >> 4, h = bh & 15, l0 = lt * 32;
    const int tid = threadIdx.x, wave = tid >> 6, lane = tid & 63;
    const int lrow = lane & 15, g8 = (lane >> 4) << 3, row4 = (lane >> 4) << 2;
    short8v qf[2][2];
#pragma unroll
    for (int mt = 0; mt < 2; ++mt)
#pragma unroll
        for (int ks = 0; ks < 2; ++ks)
            qf[mt][ks] = *(const short8v*)&qh[((size_t)bh * 1024 + l0 + mt * 16 + lrow) * 64 + ks * 32 + g8];
    float4v opv[2] = {};
    if (tid < 32) { mL[tid] = -3e38f; sL[tid] = 0.f; }
    __syncthreads();
    const int tl = tid >> 3, tr8 = tid & 7;
    const int keyS = ((tl >> 2) & 3) << 4;
    const int keyP = (tl & 7) << 3;
    for (int rt = 0; rt < 16; ++rt) {
        const int r0 = rt * 64;
        float4v sacc[2] = {};
#pragma unroll
        for (int ks = 0; ks < 2; ++ks) {
            short8v kf = *(const short8v*)&kh[((size_t)bh * 1024 + r0 + wave * 16 + lrow) * 64 + ks * 32 + g8];
            sacc[0] = MFMA16(qf[0][ks], kf, sacc[0]);
            sacc[1] = MFMA16(qf[1][ks], kf, sacc[1]);
        }
#pragma unroll
        for (int mt = 0; mt < 2; ++mt)
#pragma unroll
            for (int j = 0; j < 4; ++j) {
                const int ll = mt * 16 + row4 + j;
                const int cc = wave * 16 + lrow;
                scL[ll * 64 + (cc ^ (((ll >> 2) & 3) << 4))] = sacc[mt][j];
            }
        __syncthreads();
        float4v x0 = *(const float4v*)&scL[tl * 64 + ((tr8 * 8) ^ keyS)];
        float4v x1 = *(const float4v*)&scL[tl * 64 + ((tr8 * 8 + 4) ^ keyS)];
        short8v sbv = *(const short8v*)&sb[((size_t)(l0 + tl) * 64 + bh) * 1024 + r0 + tr8 * 8];
        float4v mk0 = *(const float4v*)&mask[(size_t)b * 1024 + r0 + tr8 * 8];
        float4v mk1 = *(const float4v*)&mask[(size_t)b * 1024 + r0 + tr8 * 8 + 4];
        float s8[8];
#pragma unroll
        for (int i = 0; i < 4; ++i) {
            s8[i]     = (x0[i] + b2f((unsigned short)sbv[i])) * 0.125f + mk0[i];
            s8[i + 4] = (x1[i] + b2f((unsigned short)sbv[i + 4])) * 0.125f + mk1[i];
        }
        {
            float4v o0, o1;
#pragma unroll
            for (int i = 0; i < 4; ++i) { o0[i] = s8[i]; o1[i] = s8[i + 4]; }
            float* sgp = &scores[((size_t)bh * 1024 + l0 + tl) * 1024 + r0 + tr8 * 8];
            *(float4v*)sgp = o0; *(float4v*)(sgp + 4) = o1;
        }
        float tm = s8[0];
#pragma unroll
        for (int i = 1; i < 8; ++i) tm = fmaxf(tm, s8[i]);
        tm = fmaxf(tm, __shfl_xor(tm, 1));
        tm = fmaxf(tm, __shfl_xor(tm, 2));
        tm = fmaxf(tm, __shfl_xor(tm, 4));
        const float mold = mL[tl];
        const float mnew = fmaxf(mold, tm);
        const float f = __expf(mold - mnew);
        float psum = 0.f;
        float p8[8];
#pragma unroll
        for (int i = 0; i < 8; ++i) { p8[i] = __expf(s8[i] - mnew); psum += p8[i]; }
        psum += __shfl_xor(psum, 1);
        psum += __shfl_xor(psum, 2);
        psum += __shfl_xor(psum, 4);
        if (tr8 == 0) { sL[tl] = sL[tl] * f + psum; mL[tl] = mnew; fL[tl] = f; }
        short8v pk;
#pragma unroll
        for (int i = 0; i < 8; ++i) pk[i] = (short)f2b(p8[i]);
        *(short8v*)&pL[tl * 64 + ((tr8 * 8) ^ keyP)] = pk;
        __syncthreads();
#pragma unroll
        for (int mt = 0; mt < 2; ++mt)
#pragma unroll
            for (int j = 0; j < 4; ++j) opv[mt][j] *= fL[mt * 16 + row4 + j];
#pragma unroll
        for (int ks = 0; ks < 2; ++ks) {
            short8v pf0 = *(const short8v*)&pL[(lrow) * 64 + ((ks * 32 + g8) ^ ((lrow & 7) << 3))];
            short8v pf1 = *(const short8v*)&pL[(16 + lrow) * 64 + ((ks * 32 + g8) ^ ((lrow & 7) << 3))];
            short8v vf = *(const short8v*)&vT[((size_t)bh * 64 + wave * 16 + lrow) * 1024 + r0 + ks * 32 + g8];
            opv[0] = MFMA16(pf0, vf, opv[0]);
            opv[1] = MFMA16(pf1, vf, opv[1]);
        }
    }
#pragma unroll
    for (int mt = 0; mt < 2; ++mt)
#pragma unroll
        for (int j = 0; j < 4; ++j) {
            const int l = mt * 16 + row4 + j;
            const float inv = 1.f / sL[l];
            const int d = wave * 16 + lrow;
            ctx[((size_t)b * 1024 + l0 + l) * 1024 + h * 64 + d] = opv[mt][j] * inv;
        }
}

// ---------------------------------------------------------------------------
extern "C" void kernel_launch(void* const* d_in, const int* in_sizes, int n_in,
                              void* d_out, int out_size, void* d_ws, size_t ws_size,
                              hipStream_t stream) {
    (void)in_sizes; (void)n_in; (void)out_size; (void)ws_size;
    const float* hidden = (const float*)d_in[0];
    const float* mask   = (const float*)d_in[1];
    const float* S      = (const float*)d_in[2];
    const float* Wq  = (const float*)d_in[3];  const float* bq  = (const float*)d_in[4];
    const float* Wk  = (const float*)d_in[5];  const float* bk  = (const float*)d_in[6];
    const float* Wv  = (const float*)d_in[7];  const float* bv  = (const float*)d_in[8];
    const float* Wsq = (const float*)d_in[9];  const float* bsq = (const float*)d_in[10];
    const float* Wsk = (const float*)d_in[11]; const float* bsk = (const float*)d_in[12];

    float* ctx    = (float*)d_out;
    float* scores = ctx + (size_t)4 * 1024 * 1024;

    char* ws = (char*)d_ws;
    unsigned short* sbuf = (unsigned short*)ws;                 // [1024][64][1024] bf16, 128 MB
    unsigned short* hb  = (unsigned short*)ws;                  // stage-1 temps alias sbuf
    unsigned short* Wqb = (unsigned short*)(ws + (8u << 20));
    unsigned short* Wkb = (unsigned short*)(ws + (10u << 20));
    unsigned short* Wvb = (unsigned short*)(ws + (12u << 20));
    unsigned short* qh  = (unsigned short*)(ws + (size_t)(128u) * 1024 * 1024);
    unsigned short* kh  = qh  + (size_t)4 * 1024 * 1024;
    unsigned short* vT  = kh  + (size_t)4 * 1024 * 1024;
    unsigned short* q2b = vT  + (size_t)4 * 1024 * 1024;
    unsigned short* k2b = q2b + (size_t)4 * 1024 * 1024;
    float* qbv = (float*)(k2b + (size_t)4 * 1024 * 1024);
    float* kbv = qbv + 65536;

    pack_all<<<3584, 256, 0, stream>>>(hidden, Wq, Wk, Wv, hb, Wqb, Wkb, Wvb);
    qkv_gemm<<<dim3(16, 32), 256, 0, stream>>>(hb, Wqb, bq, qh, 0);
    qkv_gemm<<<dim3(16, 32), 256, 0, stream>>>(hb, Wkb, bk, kh, 0);
    qkv_gemm<<<dim3(16, 32), 256, 0, stream>>>(hb, Wvb, bv, vT, 1);
    headproj<<<1024, 256, 0, stream>>>(qh, Wsq, bsq, q2b, qbv);
    headproj<<<1024, 256, 0, stream>>>(kh, Wsk, bsk, k2b, kbv);
    struct_fused<<<dim3(64, 64), 256, 0, stream>>>(S, q2b, k2b, qbv, kbv, sbuf);
    flash_kernel<<<2048, 256, 0, stream>>>(qh, kh, vT, sbuf, mask, scores, ctx);
}